// Round 2
// baseline (573.420 us; speedup 1.0000x reference)
//
#include <hip/hip_runtime.h>

typedef __attribute__((ext_vector_type(4))) float f32x4;
typedef __attribute__((ext_vector_type(4))) unsigned int u32x4;
typedef __attribute__((ext_vector_type(8))) short s16x8;

#define B_  128
#define P_  196
#define E_  2048
#define D_  512
#define A_  512
#define M_  (B_*P_)   // 25088

#define LSTR 34       // LDS row stride in shorts (68B = 17-bank stride, coprime 32)
#define BUFS (128*LSTR)

// ---------------------------------------------------------------------------
// Kernel W: transpose + round-to-nearest bf16: We[E][A] -> WeT[A][E]
// ---------------------------------------------------------------------------
__global__ void we_conv_kernel(const float* __restrict__ We,
                               unsigned short* __restrict__ WeT) {
  __shared__ float tile[32][33];
  const int tx = threadIdx.x, ty = threadIdx.y;
  const int a0 = blockIdx.x * 32, e0 = blockIdx.y * 32;
  tile[ty][tx] = We[(e0 + ty) * A_ + a0 + tx];
  __syncthreads();
  const float v = tile[tx][ty];              // = We[e0+tx][a0+ty]
  const unsigned int u = __float_as_uint(v);
  const unsigned short r = (unsigned short)((u + 0x7fffu + ((u >> 16) & 1u)) >> 16);
  WeT[(a0 + ty) * E_ + e0 + tx] = r;         // coalesced over tx
}

// ---------------------------------------------------------------------------
// Kernel A: att2pb[b][a] = decoder_hidden[b] @ Wd + bd[a] + be[a]  (fp32)
// ---------------------------------------------------------------------------
__global__ void att2_kernel(const float* __restrict__ h, const float* __restrict__ Wd,
                            const float* __restrict__ bd, const float* __restrict__ be,
                            float* __restrict__ att2pb) {
  const int b = blockIdx.x;
  const int t = threadIdx.x;  // 256
  __shared__ float hs[D_];
  hs[t] = h[b * D_ + t];
  hs[t + 256] = h[b * D_ + t + 256];
  __syncthreads();
  float a0 = 0.f, a1 = 0.f;
  for (int d = 0; d < D_; ++d) {
    const float hv = hs[d];
    a0 = fmaf(hv, Wd[d * A_ + t], a0);
    a1 = fmaf(hv, Wd[d * A_ + t + 256], a1);
  }
  att2pb[b * A_ + t] = a0 + bd[t] + be[t];
  att2pb[b * A_ + t + 256] = a1 + bd[t + 256] + be[t + 256];
}

// ---------------------------------------------------------------------------
// split 16 fp32 -> bf16 hi (trunc) + bf16 lo (residual, trunc)
// ---------------------------------------------------------------------------
__device__ inline void cvt16(const f32x4* a, s16x8* hi, s16x8* lo) {
#pragma unroll
  for (int q = 0; q < 2; ++q) {
    s16x8 h, l;
#pragma unroll
    for (int i = 0; i < 8; ++i) {
      const float v = a[2 * q + (i >> 2)][i & 3];
      const unsigned int u = __float_as_uint(v);
      h[i] = (short)(u >> 16);
      const float lf = v - __uint_as_float(u & 0xffff0000u);
      l[i] = (short)(__float_as_uint(lf) >> 16);
    }
    hi[q] = h;
    lo[q] = l;
  }
}

// ---------------------------------------------------------------------------
// Kernel B v2: scores. 128x128 tile, 2-pass split-bf16 MFMA
//   att1 = (ah+al) @ bh_rne;  epilogue relu(att1+att2)·Wf row-reduce.
// Double-buffered LDS, 1 barrier per 32-K step, prefetch loads issued first.
// grid = 784 (196 m-tiles x 4 n-blocks), bijective XCD swizzle (784 = 8*98).
// ---------------------------------------------------------------------------
__launch_bounds__(256, 3)
__global__ void score_kernel(const float* __restrict__ enc,
                             const unsigned short* __restrict__ WeT,
                             const float* __restrict__ att2pb,
                             const float* __restrict__ Wf,
                             float* __restrict__ att_part) {
  __shared__ unsigned short Ah[2 * BUFS];
  __shared__ unsigned short Al[2 * BUFS];
  __shared__ unsigned short Bh[2 * BUFS];

  const int orig = blockIdx.x;
  const int bid = (orig & 7) * 98 + (orig >> 3);   // same-XCD chunks of 98
  const int mb = bid >> 2, nb = bid & 3;
  const int m0 = mb * 128, n0 = nb * 128;

  const int t = threadIdx.x, lane = t & 63, w = t >> 6;
  const int wm = (w >> 1) * 64, wn = (w & 1) * 64;

  // staging mapping: thread t -> row t>>1, 16 k-shorts at (t&1)*16
  const int sr = t >> 1, sh = (t & 1) * 16;
  const float* ap = enc + (size_t)(m0 + sr) * E_ + sh;
  const unsigned short* bp = WeT + (size_t)(n0 + sr) * E_ + sh;
  const int woff = sr * LSTR + sh;

  // fragment read offsets
  const int koff = (lane >> 4) * 8;
  const int fa = (wm + (lane & 15)) * LSTR + koff;
  const int fb = (wn + (lane & 15)) * LSTR + koff;

  const f32x4 zero = {0.f, 0.f, 0.f, 0.f};
  f32x4 acc[4][4];
#pragma unroll
  for (int mi = 0; mi < 4; ++mi)
#pragma unroll
    for (int ni = 0; ni < 4; ++ni) acc[mi][ni] = zero;

  f32x4 ar[4];
  u32x4 br0, br1;
  s16x8 hh[2], ll[2];

  // ---- prologue: stage k0 = 0 into buf 0
  ar[0] = *(const f32x4*)(ap);
  ar[1] = *(const f32x4*)(ap + 4);
  ar[2] = *(const f32x4*)(ap + 8);
  ar[3] = *(const f32x4*)(ap + 12);
  br0 = *(const u32x4*)(bp);
  br1 = *(const u32x4*)(bp + 8);
  cvt16(ar, hh, ll);
  *(s16x8*)(Ah + woff) = hh[0];  *(s16x8*)(Ah + woff + 8) = hh[1];
  *(s16x8*)(Al + woff) = ll[0];  *(s16x8*)(Al + woff + 8) = ll[1];
  *(u32x4*)(Bh + woff) = br0;    *(u32x4*)(Bh + woff + 8) = br1;
  __syncthreads();

  int cur = 0;
  for (int it = 0; it < 63; ++it) {
    const int k1 = (it + 1) * 32;
    // issue next-tile global loads first (overlap with compute below)
    ar[0] = *(const f32x4*)(ap + k1);
    ar[1] = *(const f32x4*)(ap + k1 + 4);
    ar[2] = *(const f32x4*)(ap + k1 + 8);
    ar[3] = *(const f32x4*)(ap + k1 + 12);
    br0 = *(const u32x4*)(bp + k1);
    br1 = *(const u32x4*)(bp + k1 + 8);

    // compute current tile
    {
      const unsigned short* AhC = Ah + cur * BUFS;
      const unsigned short* AlC = Al + cur * BUFS;
      const unsigned short* BhC = Bh + cur * BUFS;
      s16x8 fah[4], fal[4], fbh[4];
#pragma unroll
      for (int i = 0; i < 4; ++i) {
        fah[i] = *(const s16x8*)(AhC + fa + i * 16 * LSTR);
        fal[i] = *(const s16x8*)(AlC + fa + i * 16 * LSTR);
        fbh[i] = *(const s16x8*)(BhC + fb + i * 16 * LSTR);
      }
#pragma unroll
      for (int mi = 0; mi < 4; ++mi)
#pragma unroll
        for (int ni = 0; ni < 4; ++ni)
          acc[mi][ni] = __builtin_amdgcn_mfma_f32_16x16x32_bf16(fah[mi], fbh[ni], acc[mi][ni], 0, 0, 0);
#pragma unroll
      for (int mi = 0; mi < 4; ++mi)
#pragma unroll
        for (int ni = 0; ni < 4; ++ni)
          acc[mi][ni] = __builtin_amdgcn_mfma_f32_16x16x32_bf16(fal[mi], fbh[ni], acc[mi][ni], 0, 0, 0);
    }

    // stage next tile into the other buffer
    {
      const int nxt = cur ^ 1;
      cvt16(ar, hh, ll);
      unsigned short* AhN = Ah + nxt * BUFS;
      unsigned short* AlN = Al + nxt * BUFS;
      unsigned short* BhN = Bh + nxt * BUFS;
      *(s16x8*)(AhN + woff) = hh[0];  *(s16x8*)(AhN + woff + 8) = hh[1];
      *(s16x8*)(AlN + woff) = ll[0];  *(s16x8*)(AlN + woff + 8) = ll[1];
      *(u32x4*)(BhN + woff) = br0;    *(u32x4*)(BhN + woff + 8) = br1;
    }
    __syncthreads();
    cur ^= 1;
  }

  // final tile compute (no staging)
  {
    const unsigned short* AhC = Ah + cur * BUFS;
    const unsigned short* AlC = Al + cur * BUFS;
    const unsigned short* BhC = Bh + cur * BUFS;
    s16x8 fah[4], fal[4], fbh[4];
#pragma unroll
    for (int i = 0; i < 4; ++i) {
      fah[i] = *(const s16x8*)(AhC + fa + i * 16 * LSTR);
      fal[i] = *(const s16x8*)(AlC + fa + i * 16 * LSTR);
      fbh[i] = *(const s16x8*)(BhC + fb + i * 16 * LSTR);
    }
#pragma unroll
    for (int mi = 0; mi < 4; ++mi)
#pragma unroll
      for (int ni = 0; ni < 4; ++ni)
        acc[mi][ni] = __builtin_amdgcn_mfma_f32_16x16x32_bf16(fah[mi], fbh[ni], acc[mi][ni], 0, 0, 0);
#pragma unroll
    for (int mi = 0; mi < 4; ++mi)
#pragma unroll
      for (int ni = 0; ni < 4; ++ni)
        acc[mi][ni] = __builtin_amdgcn_mfma_f32_16x16x32_bf16(fal[mi], fbh[ni], acc[mi][ni], 0, 0, 0);
  }

  // epilogue: x = acc + att2pb[b][col]; s = sum_col relu(x)*Wf[col]
  // C/D layout: col = lane&15, row = (lane>>4)*4 + reg
  const int colL = n0 + wn + (lane & 15);
#pragma unroll
  for (int mi = 0; mi < 4; ++mi) {
    const int rowb = m0 + wm + mi * 16 + ((lane >> 4) << 2);
#pragma unroll
    for (int r = 0; r < 4; ++r) {
      const int row = rowb + r;
      const int bb = row / P_;
      float s = 0.f;
#pragma unroll
      for (int ni = 0; ni < 4; ++ni) {
        const int col = colL + ni * 16;
        const float v = acc[mi][ni][r] + att2pb[bb * A_ + col];
        s += fmaxf(v, 0.f) * Wf[col];
      }
#pragma unroll
      for (int off = 1; off < 16; off <<= 1) s += __shfl_xor(s, off);
      if ((lane & 15) == 0) att_part[row * 8 + nb * 2 + (w & 1)] = s;
    }
  }
}

// ---------------------------------------------------------------------------
// Kernel C: per (b, e-chunk): sum partials -> softmax over P -> alpha,
// awe[b][e] = sum_p alpha[p] * enc[b][p][e].  grid = B*2, block 256.
// ---------------------------------------------------------------------------
__global__ void softmax_awe_kernel(const float* __restrict__ enc,
                                   const float* __restrict__ att_part,
                                   float* __restrict__ out) {
  const int bid = blockIdx.x;
  const int b = bid >> 1, ch = bid & 1;
  const int t = threadIdx.x;
  __shared__ float sm[256];
  __shared__ float alpha_s[P_];

  float av = -1e30f;
  if (t < P_) {
    const float* apt = att_part + (b * P_ + t) * 8;
    float s = 0.f;
#pragma unroll
    for (int i = 0; i < 8; ++i) s += apt[i];
    av = s;
  }
  sm[t] = av;
  __syncthreads();
  for (int st = 128; st > 0; st >>= 1) {
    if (t < st) sm[t] = fmaxf(sm[t], sm[t + st]);
    __syncthreads();
  }
  const float mx = sm[0];
  __syncthreads();
  float ev = 0.f;
  if (t < P_) ev = __expf(av - mx);
  sm[t] = ev;
  __syncthreads();
  for (int st = 128; st > 0; st >>= 1) {
    if (t < st) sm[t] += sm[t + st];
    __syncthreads();
  }
  const float denom = sm[0];
  const float al = ev / denom;
  if (t < P_) {
    alpha_s[t] = al;
    if (ch == 0) out[B_ * E_ + b * P_ + t] = al;   // alpha output
  }
  __syncthreads();

  const int e0 = ch * 1024 + t * 4;
  const float* ebase = enc + (size_t)b * P_ * E_ + e0;
  f32x4 acc = {0.f, 0.f, 0.f, 0.f};
  for (int p = 0; p < P_; ++p) {
    const f32x4 v = *(const f32x4*)(ebase + (size_t)p * E_);
    const float a = alpha_s[p];
    acc.x += a * v.x; acc.y += a * v.y; acc.z += a * v.z; acc.w += a * v.w;
  }
  *(f32x4*)(out + b * E_ + e0) = acc;
}

// ---------------------------------------------------------------------------
extern "C" void kernel_launch(void* const* d_in, const int* in_sizes, int n_in,
                              void* d_out, int out_size, void* d_ws, size_t ws_size,
                              hipStream_t stream) {
  const float* enc = (const float*)d_in[0];
  const float* h   = (const float*)d_in[1];
  const float* We  = (const float*)d_in[2];
  const float* be  = (const float*)d_in[3];
  const float* Wd  = (const float*)d_in[4];
  const float* bd  = (const float*)d_in[5];
  const float* Wf  = (const float*)d_in[6];
  // d_in[7] = bf: constant shift before softmax -> cancels; unused.
  float* out = (float*)d_out;

  // workspace layout (~3.1 MB)
  float* att2pb = (float*)d_ws;                       // 128*512 f32
  float* att_part = att2pb + B_ * A_;                 // 25088*8 f32
  unsigned short* WeT = (unsigned short*)(att_part + M_ * 8);  // 512*2048 u16

  we_conv_kernel<<<dim3(A_ / 32, E_ / 32), dim3(32, 32), 0, stream>>>(We, WeT);
  att2_kernel<<<B_, 256, 0, stream>>>(h, Wd, bd, be, att2pb);
  score_kernel<<<(M_ / 128) * 4, 256, 0, stream>>>(enc, WeT, att2pb, Wf, att_part);
  softmax_awe_kernel<<<B_ * 2, 256, 0, stream>>>(enc, att_part, out);
}

// Round 3
// 341.196 us; speedup vs baseline: 1.6806x; 1.6806x over previous
//
#include <hip/hip_runtime.h>

typedef __attribute__((ext_vector_type(4))) float f32x4;
typedef __attribute__((ext_vector_type(4))) unsigned int u32x4;
typedef __attribute__((ext_vector_type(8))) short s16x8;

#define B_  128
#define P_  196
#define E_  2048
#define D_  512
#define A_  512
#define M_  (B_*P_)   // 25088

#define LSTR 34       // LDS row stride in shorts (68B = 17-bank stride, coprime 32)

// ---------------------------------------------------------------------------
// Kernel W: transpose + round-to-nearest bf16: We[E][A] -> WeT[A][E]
// ---------------------------------------------------------------------------
__global__ void we_conv_kernel(const float* __restrict__ We,
                               unsigned short* __restrict__ WeT) {
  __shared__ float tile[32][33];
  const int tx = threadIdx.x, ty = threadIdx.y;
  const int a0 = blockIdx.x * 32, e0 = blockIdx.y * 32;
  tile[ty][tx] = We[(e0 + ty) * A_ + a0 + tx];
  __syncthreads();
  const float v = tile[tx][ty];              // = We[e0+tx][a0+ty]
  const unsigned int u = __float_as_uint(v);
  const unsigned short r = (unsigned short)((u + 0x7fffu + ((u >> 16) & 1u)) >> 16);
  WeT[(a0 + ty) * E_ + e0 + tx] = r;         // coalesced over tx
}

// ---------------------------------------------------------------------------
// Kernel A: att2pb[b][a] = decoder_hidden[b] @ Wd + bd[a] + be[a]  (fp32)
// ---------------------------------------------------------------------------
__global__ void att2_kernel(const float* __restrict__ h, const float* __restrict__ Wd,
                            const float* __restrict__ bd, const float* __restrict__ be,
                            float* __restrict__ att2pb) {
  const int b = blockIdx.x;
  const int t = threadIdx.x;  // 256
  __shared__ float hs[D_];
  hs[t] = h[b * D_ + t];
  hs[t + 256] = h[b * D_ + t + 256];
  __syncthreads();
  float a0 = 0.f, a1 = 0.f;
  for (int d = 0; d < D_; ++d) {
    const float hv = hs[d];
    a0 = fmaf(hv, Wd[d * A_ + t], a0);
    a1 = fmaf(hv, Wd[d * A_ + t + 256], a1);
  }
  att2pb[b * A_ + t] = a0 + bd[t] + be[t];
  att2pb[b * A_ + t + 256] = a1 + bd[t + 256] + be[t + 256];
}

// ---------------------------------------------------------------------------
// split 8 fp32 -> bf16 hi (trunc) + bf16 lo (residual, trunc)
// ---------------------------------------------------------------------------
__device__ inline void split8(f32x4 u0, f32x4 u1, s16x8& hi, s16x8& lo) {
#pragma unroll
  for (int i = 0; i < 8; ++i) {
    const float v = (i < 4) ? u0[i] : u1[i - 4];
    const unsigned int u = __float_as_uint(v);
    hi[i] = (short)(u >> 16);
    const float lof = v - __uint_as_float(u & 0xffff0000u);
    lo[i] = (short)(__float_as_uint(lof) >> 16);
  }
}

// ---------------------------------------------------------------------------
// Kernel B (R0 schedule + 2-pass + conflict-free LDS + XCD swizzle):
// 128x128 tile of att1 = (Ah+Al) @ Bh_rne, 16x16x32 bf16 MFMA,
// epilogue: relu(att1 + att2pb)*Wf row-reduce -> att_part[row][8 slots]
// grid = 784 = 196 m-tiles x 4 n-blocks; 784 = 8*98 -> bijective XCD swizzle
// ---------------------------------------------------------------------------
__launch_bounds__(256, 4)
__global__ void score_kernel(const float* __restrict__ enc,
                             const unsigned short* __restrict__ WeT,
                             const float* __restrict__ att2pb,
                             const float* __restrict__ Wf,
                             float* __restrict__ att_part) {
  __shared__ unsigned short Ah[128 * LSTR];
  __shared__ unsigned short Al[128 * LSTR];
  __shared__ unsigned short Bh[128 * LSTR];

  const int orig = blockIdx.x;
  const int bid = (orig & 7) * 98 + (orig >> 3);   // same-XCD chunks of 98
  const int mb = bid >> 2, nb = bid & 3;
  const int m0 = mb * 128, n0 = nb * 128;

  const int t = threadIdx.x;
  const int lane = t & 63, w = t >> 6;
  const int wm = (w >> 1) * 64, wn = (w & 1) * 64;

  // staging: A tile [128 rows][32 k] f32; per thread rows (t>>2) and (t>>2)+64
  const int ar = t >> 2;
  const int akc = (t & 3) * 8;
  const float* aptr = enc + (size_t)(m0 + ar) * E_ + akc;
  // B tile [128 n-rows][32 k] bf16 from WeT; per thread row t>>1, 16 shorts
  const int br = t >> 1;
  const int bkc = (t & 1) * 16;
  const unsigned short* bhp = WeT + (size_t)(n0 + br) * E_ + bkc;

  unsigned short* AhW0 = Ah + ar * LSTR + akc;
  unsigned short* AlW0 = Al + ar * LSTR + akc;
  unsigned short* AhW1 = AhW0 + 64 * LSTR;
  unsigned short* AlW1 = AlW0 + 64 * LSTR;
  unsigned short* BhW = Bh + br * LSTR + bkc;

  const f32x4 zero = {0.f, 0.f, 0.f, 0.f};
  f32x4 acc[4][4];
#pragma unroll
  for (int mi = 0; mi < 4; ++mi)
#pragma unroll
    for (int ni = 0; ni < 4; ++ni) acc[mi][ni] = zero;

  // fragment read offsets: lane&15 = row/col, (lane>>4)*8 = k offset
  const int koff = (lane >> 4) * 8;
  const int fa = (wm + (lane & 15)) * LSTR + koff;
  const int fb = (wn + (lane & 15)) * LSTR + koff;

  for (int k0 = 0; k0 < E_; k0 += 32) {
    // global loads
    const f32x4 a00 = *(const f32x4*)(aptr + k0);
    const f32x4 a01 = *(const f32x4*)(aptr + k0 + 4);
    const f32x4 a10 = *(const f32x4*)(aptr + k0 + 64 * E_);
    const f32x4 a11 = *(const f32x4*)(aptr + k0 + 64 * E_ + 4);
    const u32x4 bh0 = *(const u32x4*)(bhp + k0);
    const u32x4 bh1 = *(const u32x4*)(bhp + k0 + 8);

    s16x8 ah0, al0, ah1, al1;
    split8(a00, a01, ah0, al0);
    split8(a10, a11, ah1, al1);

    __syncthreads();   // previous iteration's fragment reads done
    *(s16x8*)AhW0 = ah0;  *(s16x8*)AlW0 = al0;
    *(s16x8*)AhW1 = ah1;  *(s16x8*)AlW1 = al1;
    *(u32x4*)BhW = bh0;   *(u32x4*)(BhW + 8) = bh1;
    __syncthreads();

    s16x8 fah[4], fal[4], fbh[4];
#pragma unroll
    for (int i = 0; i < 4; ++i) {
      fah[i] = *(const s16x8*)(Ah + fa + i * 16 * LSTR);
      fal[i] = *(const s16x8*)(Al + fa + i * 16 * LSTR);
      fbh[i] = *(const s16x8*)(Bh + fb + i * 16 * LSTR);
    }
#pragma unroll
    for (int mi = 0; mi < 4; ++mi)
#pragma unroll
      for (int ni = 0; ni < 4; ++ni)
        acc[mi][ni] = __builtin_amdgcn_mfma_f32_16x16x32_bf16(fah[mi], fbh[ni], acc[mi][ni], 0, 0, 0);
#pragma unroll
    for (int mi = 0; mi < 4; ++mi)
#pragma unroll
      for (int ni = 0; ni < 4; ++ni)
        acc[mi][ni] = __builtin_amdgcn_mfma_f32_16x16x32_bf16(fal[mi], fbh[ni], acc[mi][ni], 0, 0, 0);
  }

  // epilogue: x = acc + att2pb[b][col]; s = sum_col relu(x)*Wf[col]
  // C/D layout: col = lane&15, row = (lane>>4)*4 + reg   [m89/m91 verified]
  const int colL = n0 + wn + (lane & 15);
#pragma unroll
  for (int mi = 0; mi < 4; ++mi) {
    const int rowb = m0 + wm + mi * 16 + ((lane >> 4) << 2);
#pragma unroll
    for (int r = 0; r < 4; ++r) {
      const int row = rowb + r;
      const int bb = row / P_;
      float s = 0.f;
#pragma unroll
      for (int ni = 0; ni < 4; ++ni) {
        const int col = colL + ni * 16;
        const float v = acc[mi][ni][r] + att2pb[bb * A_ + col];
        s += fmaxf(v, 0.f) * Wf[col];
      }
#pragma unroll
      for (int off = 1; off < 16; off <<= 1) s += __shfl_xor(s, off);
      if ((lane & 15) == 0) att_part[row * 8 + nb * 2 + (w & 1)] = s;
    }
  }
}

// ---------------------------------------------------------------------------
// Kernel C: per (b, e-chunk): sum partials -> softmax over P -> alpha,
// awe[b][e] = sum_p alpha[p] * enc[b][p][e].  grid = B*2, block 256.
// ---------------------------------------------------------------------------
__global__ void softmax_awe_kernel(const float* __restrict__ enc,
                                   const float* __restrict__ att_part,
                                   float* __restrict__ out) {
  const int bid = blockIdx.x;
  const int b = bid >> 1, ch = bid & 1;
  const int t = threadIdx.x;
  __shared__ float sm[256];
  __shared__ float alpha_s[P_];

  float av = -1e30f;
  if (t < P_) {
    const float* apt = att_part + (b * P_ + t) * 8;
    float s = 0.f;
#pragma unroll
    for (int i = 0; i < 8; ++i) s += apt[i];
    av = s;
  }
  sm[t] = av;
  __syncthreads();
  for (int st = 128; st > 0; st >>= 1) {
    if (t < st) sm[t] = fmaxf(sm[t], sm[t + st]);
    __syncthreads();
  }
  const float mx = sm[0];
  __syncthreads();
  float ev = 0.f;
  if (t < P_) ev = __expf(av - mx);
  sm[t] = ev;
  __syncthreads();
  for (int st = 128; st > 0; st >>= 1) {
    if (t < st) sm[t] += sm[t + st];
    __syncthreads();
  }
  const float denom = sm[0];
  const float al = ev / denom;
  if (t < P_) {
    alpha_s[t] = al;
    if (ch == 0) out[B_ * E_ + b * P_ + t] = al;   // alpha output
  }
  __syncthreads();

  const int e0 = ch * 1024 + t * 4;
  const float* ebase = enc + (size_t)b * P_ * E_ + e0;
  f32x4 acc = {0.f, 0.f, 0.f, 0.f};
  for (int p = 0; p < P_; ++p) {
    const f32x4 v = *(const f32x4*)(ebase + (size_t)p * E_);
    const float a = alpha_s[p];
    acc.x += a * v.x; acc.y += a * v.y; acc.z += a * v.z; acc.w += a * v.w;
  }
  *(f32x4*)(out + b * E_ + e0) = acc;
}

// ---------------------------------------------------------------------------
extern "C" void kernel_launch(void* const* d_in, const int* in_sizes, int n_in,
                              void* d_out, int out_size, void* d_ws, size_t ws_size,
                              hipStream_t stream) {
  const float* enc = (const float*)d_in[0];
  const float* h   = (const float*)d_in[1];
  const float* We  = (const float*)d_in[2];
  const float* be  = (const float*)d_in[3];
  const float* Wd  = (const float*)d_in[4];
  const float* bd  = (const float*)d_in[5];
  const float* Wf  = (const float*)d_in[6];
  // d_in[7] = bf: constant shift before softmax -> cancels; unused.
  float* out = (float*)d_out;

  // workspace layout (~3.1 MB)
  float* att2pb = (float*)d_ws;                       // 128*512 f32
  float* att_part = att2pb + B_ * A_;                 // 25088*8 f32
  unsigned short* WeT = (unsigned short*)(att_part + M_ * 8);  // 512*2048 u16

  we_conv_kernel<<<dim3(A_ / 32, E_ / 32), dim3(32, 32), 0, stream>>>(We, WeT);
  att2_kernel<<<B_, 256, 0, stream>>>(h, Wd, bd, be, att2pb);
  score_kernel<<<(M_ / 128) * 4, 256, 0, stream>>>(enc, WeT, att2pb, Wf, att_part);
  softmax_awe_kernel<<<B_ * 2, 256, 0, stream>>>(enc, att_part, out);
}

// Round 4
// 161.968 us; speedup vs baseline: 3.5403x; 2.1066x over previous
//
#include <hip/hip_runtime.h>
#include <hip/hip_bf16.h>

typedef __attribute__((ext_vector_type(4))) float f32x4;
typedef __attribute__((ext_vector_type(4))) unsigned int u32x4;
typedef __attribute__((ext_vector_type(8))) short s16x8;

#define B_  128
#define P_  196
#define E_  2048
#define D_  512
#define A_  512
#define M_  (B_*P_)   // 25088

// ---------------------------------------------------------------------------
// Kernel W: transpose + round-to-nearest bf16: We[E][A] -> WeT[A][E]
// ---------------------------------------------------------------------------
__global__ void we_conv_kernel(const float* __restrict__ We,
                               unsigned short* __restrict__ WeT) {
  __shared__ float tile[32][33];
  const int tx = threadIdx.x, ty = threadIdx.y;
  const int a0 = blockIdx.x * 32, e0 = blockIdx.y * 32;
  tile[ty][tx] = We[(e0 + ty) * A_ + a0 + tx];
  __syncthreads();
  const float v = tile[tx][ty];              // = We[e0+tx][a0+ty]
  const unsigned int u = __float_as_uint(v);
  const unsigned short r = (unsigned short)((u + 0x7fffu + ((u >> 16) & 1u)) >> 16);
  WeT[(a0 + ty) * E_ + e0 + tx] = r;         // coalesced over tx
}

// ---------------------------------------------------------------------------
// Kernel A: att2pb[b][a] = decoder_hidden[b] @ Wd + bd[a] + be[a]  (fp32)
// ---------------------------------------------------------------------------
__global__ void att2_kernel(const float* __restrict__ h, const float* __restrict__ Wd,
                            const float* __restrict__ bd, const float* __restrict__ be,
                            float* __restrict__ att2pb) {
  const int b = blockIdx.x;
  const int t = threadIdx.x;  // 256
  __shared__ float hs[D_];
  hs[t] = h[b * D_ + t];
  hs[t + 256] = h[b * D_ + t + 256];
  __syncthreads();
  float a0 = 0.f, a1 = 0.f;
  for (int d = 0; d < D_; ++d) {
    const float hv = hs[d];
    a0 = fmaf(hv, Wd[d * A_ + t], a0);
    a1 = fmaf(hv, Wd[d * A_ + t + 256], a1);
  }
  att2pb[b * A_ + t] = a0 + bd[t] + be[t];
  att2pb[b * A_ + t + 256] = a1 + bd[t + 256] + be[t + 256];
}

// ---------------------------------------------------------------------------
// rne pack helpers: 2 f32 -> packed 2 bf16 (v_cvt_pk_bf16_f32 via compiler)
// ---------------------------------------------------------------------------
__device__ inline unsigned pk2(float a, float b) {
  union { __hip_bfloat162 h; unsigned u; } cv;
  cv.h = __float22bfloat162_rn(make_float2(a, b));
  return cv.u;
}
__device__ inline u32x4 cvt8(const f32x4 lo, const f32x4 hi) {
  u32x4 r;
  r[0] = pk2(lo[0], lo[1]);
  r[1] = pk2(lo[2], lo[3]);
  r[2] = pk2(hi[0], hi[1]);
  r[3] = pk2(hi[2], hi[3]);
  return r;
}

// ---------------------------------------------------------------------------
// Kernel B v3: 1-pass bf16 (A=rne(enc) on the fly, B=rne WeT), 128x128 tile,
// XOR-swizzled linear LDS (conflict-free writes AND fragment reads),
// R2 schedule: load -> cvt -> bar -> write -> bar -> read -> 16 MFMA per K=32.
// grid = 784 = 196 m-tiles x 4 n-blocks; bijective XCD swizzle (784 = 8*98).
// swizzle: shortoff(r, chunk) = (r*32 + chunk*8) ^ ((r&7)<<3)   [16B chunks]
// ---------------------------------------------------------------------------
__launch_bounds__(256, 4)
__global__ void score_kernel(const float* __restrict__ enc,
                             const unsigned short* __restrict__ WeT,
                             const float* __restrict__ att2pb,
                             const float* __restrict__ Wf,
                             float* __restrict__ att_part) {
  __shared__ unsigned short Ah[4096];   // 128 rows x 32 k, swizzled
  __shared__ unsigned short Bh[4096];

  const int orig = blockIdx.x;
  const int bid = (orig & 7) * 98 + (orig >> 3);   // same-XCD chunks of 98
  const int mb = bid >> 2, nb = bid & 3;
  const int m0 = mb * 128, n0 = nb * 128;

  const int t = threadIdx.x;
  const int lane = t & 63, w = t >> 6;
  const int wm = (w >> 1) * 64, wn = (w & 1) * 64;

  // A staging: rows ar and ar+64, 8 floats (one 16B bf16 chunk) at chunk t&3
  const int ar = t >> 2, ac = t & 3;
  const float* aptr = enc + (size_t)(m0 + ar) * E_ + ac * 8;
  const int awz0 = (ar * 32 + ac * 8) ^ ((ar & 7) << 3);
  const int awz1 = ((ar + 64) * 32 + ac * 8) ^ ((ar & 7) << 3);
  // B staging: row br, two 16B chunks (2h, 2h+1)
  const int br = t >> 1, bhf = t & 1;
  const unsigned short* bptr = WeT + (size_t)(n0 + br) * E_ + bhf * 16;
  const int bwz0 = (br * 32 + bhf * 16) ^ ((br & 7) << 3);
  const int bwz1 = (br * 32 + bhf * 16 + 8) ^ ((br & 7) << 3);

  // fragment read offsets: row = w-tile + i*16 + (lane&15), k-chunk = lane>>4
  const int q = lane >> 4, fr = lane & 15;
  const int fxor = (fr & 7) << 3;
  int fa[4], fb[4];
#pragma unroll
  for (int i = 0; i < 4; ++i) {
    fa[i] = ((wm + i * 16 + fr) * 32 + q * 8) ^ fxor;
    fb[i] = ((wn + i * 16 + fr) * 32 + q * 8) ^ fxor;
  }

  const f32x4 zero = {0.f, 0.f, 0.f, 0.f};
  f32x4 acc[4][4];
#pragma unroll
  for (int mi = 0; mi < 4; ++mi)
#pragma unroll
    for (int ni = 0; ni < 4; ++ni) acc[mi][ni] = zero;

  for (int k0 = 0; k0 < E_; k0 += 32) {
    // global loads (A: two rows x 32B, full 128B lines per instr; B: bf16)
    const f32x4 a00 = *(const f32x4*)(aptr + k0);
    const f32x4 a01 = *(const f32x4*)(aptr + k0 + 4);
    const f32x4 a10 = *(const f32x4*)(aptr + k0 + 64 * E_);
    const f32x4 a11 = *(const f32x4*)(aptr + k0 + 64 * E_ + 4);
    const u32x4 b0 = *(const u32x4*)(bptr + k0);
    const u32x4 b1 = *(const u32x4*)(bptr + k0 + 8);

    const u32x4 av0 = cvt8(a00, a01);
    const u32x4 av1 = cvt8(a10, a11);

    __syncthreads();   // previous iteration's fragment reads done
    *(u32x4*)(Ah + awz0) = av0;
    *(u32x4*)(Ah + awz1) = av1;
    *(u32x4*)(Bh + bwz0) = b0;
    *(u32x4*)(Bh + bwz1) = b1;
    __syncthreads();

    s16x8 fah[4], fbh[4];
#pragma unroll
    for (int i = 0; i < 4; ++i) {
      fah[i] = *(const s16x8*)(Ah + fa[i]);
      fbh[i] = *(const s16x8*)(Bh + fb[i]);
    }
#pragma unroll
    for (int mi = 0; mi < 4; ++mi)
#pragma unroll
      for (int ni = 0; ni < 4; ++ni)
        acc[mi][ni] = __builtin_amdgcn_mfma_f32_16x16x32_bf16(fah[mi], fbh[ni], acc[mi][ni], 0, 0, 0);
  }

  // epilogue: x = acc + att2pb[b][col]; s = sum_col relu(x)*Wf[col]
  // C/D layout: col = lane&15, row = (lane>>4)*4 + reg   [m89/m91 verified]
  const int colL = n0 + wn + (lane & 15);
#pragma unroll
  for (int mi = 0; mi < 4; ++mi) {
    const int rowb = m0 + wm + mi * 16 + ((lane >> 4) << 2);
#pragma unroll
    for (int r = 0; r < 4; ++r) {
      const int row = rowb + r;
      const int bb = row / P_;
      float s = 0.f;
#pragma unroll
      for (int ni = 0; ni < 4; ++ni) {
        const int col = colL + ni * 16;
        const float v = acc[mi][ni][r] + att2pb[bb * A_ + col];
        s += fmaxf(v, 0.f) * Wf[col];
      }
#pragma unroll
      for (int off = 1; off < 16; off <<= 1) s += __shfl_xor(s, off);
      if ((lane & 15) == 0) att_part[row * 8 + nb * 2 + (w & 1)] = s;
    }
  }
}

// ---------------------------------------------------------------------------
// Kernel C: per (b, e-chunk): sum partials -> softmax over P -> alpha,
// awe[b][e] = sum_p alpha[p] * enc[b][p][e].  grid = B*2, block 256.
// ---------------------------------------------------------------------------
__global__ void softmax_awe_kernel(const float* __restrict__ enc,
                                   const float* __restrict__ att_part,
                                   float* __restrict__ out) {
  const int bid = blockIdx.x;
  const int b = bid >> 1, ch = bid & 1;
  const int t = threadIdx.x;
  __shared__ float sm[256];
  __shared__ float alpha_s[P_];

  float av = -1e30f;
  if (t < P_) {
    const float* apt = att_part + (b * P_ + t) * 8;
    float s = 0.f;
#pragma unroll
    for (int i = 0; i < 8; ++i) s += apt[i];
    av = s;
  }
  sm[t] = av;
  __syncthreads();
  for (int st = 128; st > 0; st >>= 1) {
    if (t < st) sm[t] = fmaxf(sm[t], sm[t + st]);
    __syncthreads();
  }
  const float mx = sm[0];
  __syncthreads();
  float ev = 0.f;
  if (t < P_) ev = __expf(av - mx);
  sm[t] = ev;
  __syncthreads();
  for (int st = 128; st > 0; st >>= 1) {
    if (t < st) sm[t] += sm[t + st];
    __syncthreads();
  }
  const float denom = sm[0];
  const float al = ev / denom;
  if (t < P_) {
    alpha_s[t] = al;
    if (ch == 0) out[B_ * E_ + b * P_ + t] = al;   // alpha output
  }
  __syncthreads();

  const int e0 = ch * 1024 + t * 4;
  const float* ebase = enc + (size_t)b * P_ * E_ + e0;
  f32x4 acc = {0.f, 0.f, 0.f, 0.f};
  for (int p = 0; p < P_; ++p) {
    const f32x4 v = *(const f32x4*)(ebase + (size_t)p * E_);
    const float a = alpha_s[p];
    acc.x += a * v.x; acc.y += a * v.y; acc.z += a * v.z; acc.w += a * v.w;
  }
  *(f32x4*)(out + b * E_ + e0) = acc;
}

// ---------------------------------------------------------------------------
extern "C" void kernel_launch(void* const* d_in, const int* in_sizes, int n_in,
                              void* d_out, int out_size, void* d_ws, size_t ws_size,
                              hipStream_t stream) {
  const float* enc = (const float*)d_in[0];
  const float* h   = (const float*)d_in[1];
  const float* We  = (const float*)d_in[2];
  const float* be  = (const float*)d_in[3];
  const float* Wd  = (const float*)d_in[4];
  const float* bd  = (const float*)d_in[5];
  const float* Wf  = (const float*)d_in[6];
  // d_in[7] = bf: constant shift before softmax -> cancels; unused.
  float* out = (float*)d_out;

  // workspace layout (~3.1 MB)
  float* att2pb = (float*)d_ws;                       // 128*512 f32
  float* att_part = att2pb + B_ * A_;                 // 25088*8 f32
  unsigned short* WeT = (unsigned short*)(att_part + M_ * 8);  // 512*2048 u16

  we_conv_kernel<<<dim3(A_ / 32, E_ / 32), dim3(32, 32), 0, stream>>>(We, WeT);
  att2_kernel<<<B_, 256, 0, stream>>>(h, Wd, bd, be, att2pb);
  score_kernel<<<(M_ / 128) * 4, 256, 0, stream>>>(enc, WeT, att2pb, Wf, att_part);
  softmax_awe_kernel<<<B_ * 2, 256, 0, stream>>>(enc, att_part, out);
}

// Round 5
// 161.718 us; speedup vs baseline: 3.5458x; 1.0015x over previous
//
#include <hip/hip_runtime.h>
#include <hip/hip_bf16.h>

typedef __attribute__((ext_vector_type(4))) float f32x4;
typedef __attribute__((ext_vector_type(4))) unsigned int u32x4;
typedef __attribute__((ext_vector_type(8))) short s16x8;

#define B_  128
#define P_  196
#define E_  2048
#define D_  512
#define A_  512
#define M_  (B_*P_)   // 25088

// ---------------------------------------------------------------------------
// Kernel W: transpose + round-to-nearest bf16: We[E][A] -> WeT[A][E]
// ---------------------------------------------------------------------------
__global__ void we_conv_kernel(const float* __restrict__ We,
                               unsigned short* __restrict__ WeT) {
  __shared__ float tile[32][33];
  const int tx = threadIdx.x, ty = threadIdx.y;
  const int a0 = blockIdx.x * 32, e0 = blockIdx.y * 32;
  tile[ty][tx] = We[(e0 + ty) * A_ + a0 + tx];
  __syncthreads();
  const float v = tile[tx][ty];              // = We[e0+tx][a0+ty]
  const unsigned int u = __float_as_uint(v);
  const unsigned short r = (unsigned short)((u + 0x7fffu + ((u >> 16) & 1u)) >> 16);
  WeT[(a0 + ty) * E_ + e0 + tx] = r;         // coalesced over tx
}

// ---------------------------------------------------------------------------
// Kernel A: att2pb[b][a] = decoder_hidden[b] @ Wd + bd[a] + be[a]  (fp32)
// ---------------------------------------------------------------------------
__global__ void att2_kernel(const float* __restrict__ h, const float* __restrict__ Wd,
                            const float* __restrict__ bd, const float* __restrict__ be,
                            float* __restrict__ att2pb) {
  const int b = blockIdx.x;
  const int t = threadIdx.x;  // 256
  __shared__ float hs[D_];
  hs[t] = h[b * D_ + t];
  hs[t + 256] = h[b * D_ + t + 256];
  __syncthreads();
  float a0 = 0.f, a1 = 0.f;
  for (int d = 0; d < D_; ++d) {
    const float hv = hs[d];
    a0 = fmaf(hv, Wd[d * A_ + t], a0);
    a1 = fmaf(hv, Wd[d * A_ + t + 256], a1);
  }
  att2pb[b * A_ + t] = a0 + bd[t] + be[t];
  att2pb[b * A_ + t + 256] = a1 + bd[t + 256] + be[t + 256];
}

// ---------------------------------------------------------------------------
// rne pack helpers: 2 f32 -> packed 2 bf16 (v_cvt_pk_bf16_f32 via compiler)
// ---------------------------------------------------------------------------
__device__ inline unsigned pk2(float a, float b) {
  union { __hip_bfloat162 h; unsigned u; } cv;
  cv.h = __float22bfloat162_rn(make_float2(a, b));
  return cv.u;
}
__device__ inline u32x4 cvt8(const f32x4 lo, const f32x4 hi) {
  u32x4 r;
  r[0] = pk2(lo[0], lo[1]);
  r[1] = pk2(lo[2], lo[3]);
  r[2] = pk2(hi[0], hi[1]);
  r[3] = pk2(hi[2], hi[3]);
  return r;
}

// ---------------------------------------------------------------------------
// Kernel B v4: full-N strip per block. Block tile 128m x 512n, 8 waves
// (2m x 4n, wave tile 64x128), K-step 32, 1-pass bf16 (A=rne on the fly).
// XOR-swizzled linear LDS: shortoff(r,c8) = (r*32 + c8*8) ^ ((r&7)<<3).
// Schedule per K-step (R3-proven): load -> cvt -> bar -> write -> bar ->
// frag-read -> 32 MFMA/wave.  grid = 196, block = 512.
// ---------------------------------------------------------------------------
__launch_bounds__(512, 2)
__global__ void score_kernel(const float* __restrict__ enc,
                             const unsigned short* __restrict__ WeT,
                             const float* __restrict__ att2pb,
                             const float* __restrict__ Wf,
                             float* __restrict__ att_part) {
  __shared__ unsigned short Ah[128 * 32];   //  8 KB, swizzled
  __shared__ unsigned short Bh[512 * 32];   // 32 KB, swizzled

  const int bid = blockIdx.x;               // 0..195, no swizzle (no A-reuse)
  const int m0 = bid * 128;

  const int t = threadIdx.x;                // 0..511
  const int lane = t & 63, w = t >> 6;      // 8 waves
  const int wm = (w >> 2) * 64;             // 0 | 64
  const int wn = (w & 3) * 128;             // 0 | 128 | 256 | 384

  // A staging: row ar = t>>2 (0..127), 8 floats at chunk ac = t&3 (coalesced)
  const int ar = t >> 2, ac = t & 3;
  const float* aptr = enc + (size_t)(m0 + ar) * E_ + ac * 8;
  const int awz = (ar * 32 + ac * 8) ^ ((ar & 7) << 3);

  // B staging: rows br+128*i (i=0..3), 16B chunk ac each (coalesced: lanes
  // 0-3 cover one row's 64B)
  const int br = t >> 2;
  const unsigned short* bptr = WeT + (size_t)br * E_ + ac * 8;
  const int bx = (br & 7) << 3;
  const int bwz0 = (br * 32 + ac * 8) ^ bx;          // rows br, br+128,... share (r&7)

  // fragment read offsets: row = tile + i*16 + fr, k-chunk q = lane>>4
  const int q = lane >> 4, fr = lane & 15;
  const int fx = (fr & 7) << 3;
  int fa[4], fb[8];
#pragma unroll
  for (int i = 0; i < 4; ++i) fa[i] = ((wm + i * 16 + fr) * 32 + q * 8) ^ fx;
#pragma unroll
  for (int j = 0; j < 8; ++j) fb[j] = ((wn + j * 16 + fr) * 32 + q * 8) ^ fx;

  const f32x4 zero = {0.f, 0.f, 0.f, 0.f};
  f32x4 acc[4][8];
#pragma unroll
  for (int mi = 0; mi < 4; ++mi)
#pragma unroll
    for (int ni = 0; ni < 8; ++ni) acc[mi][ni] = zero;

  for (int k0 = 0; k0 < E_; k0 += 32) {
    // global loads: A two f32x4 (one row-chunk), B four 16B row-chunks
    const f32x4 a0 = *(const f32x4*)(aptr + k0);
    const f32x4 a1 = *(const f32x4*)(aptr + k0 + 4);
    const u32x4 b0 = *(const u32x4*)(bptr + k0);
    const u32x4 b1 = *(const u32x4*)(bptr + k0 + 128 * E_);
    const u32x4 b2 = *(const u32x4*)(bptr + k0 + 256 * E_);
    const u32x4 b3 = *(const u32x4*)(bptr + k0 + 384 * E_);
    const u32x4 av = cvt8(a0, a1);

    __syncthreads();   // previous iteration's fragment reads done
    *(u32x4*)(Ah + awz) = av;
    *(u32x4*)(Bh + bwz0) = b0;
    *(u32x4*)(Bh + (bwz0 + 128 * 32)) = b1;   // (r+128)&7 == r&7: same XOR
    *(u32x4*)(Bh + (bwz0 + 256 * 32)) = b2;
    *(u32x4*)(Bh + (bwz0 + 384 * 32)) = b3;
    __syncthreads();

    s16x8 fbh[8], fah[4];
#pragma unroll
    for (int j = 0; j < 8; ++j) fbh[j] = *(const s16x8*)(Bh + fb[j]);
#pragma unroll
    for (int i = 0; i < 4; ++i) fah[i] = *(const s16x8*)(Ah + fa[i]);
#pragma unroll
    for (int mi = 0; mi < 4; ++mi)
#pragma unroll
      for (int ni = 0; ni < 8; ++ni)
        acc[mi][ni] = __builtin_amdgcn_mfma_f32_16x16x32_bf16(fah[mi], fbh[ni], acc[mi][ni], 0, 0, 0);
  }

  // epilogue: s = sum_col relu(acc + att2pb[b][col]) * Wf[col], 16-lane reduce
  // C/D layout: col = lane&15, row = (lane>>4)*4 + reg
  const int colL = wn + fr;
  float wfv[8];
#pragma unroll
  for (int ni = 0; ni < 8; ++ni) wfv[ni] = Wf[colL + ni * 16];
#pragma unroll
  for (int mi = 0; mi < 4; ++mi) {
    const int rowb = m0 + wm + mi * 16 + (q << 2);
#pragma unroll
    for (int r = 0; r < 4; ++r) {
      const int row = rowb + r;
      const int bb = row / P_;
      const float* a2 = att2pb + bb * A_ + colL;
      float s = 0.f;
#pragma unroll
      for (int ni = 0; ni < 8; ++ni)
        s += fmaxf(acc[mi][ni][r] + a2[ni * 16], 0.f) * wfv[ni];
#pragma unroll
      for (int off = 1; off < 16; off <<= 1) s += __shfl_xor(s, off);
      if (fr == 0) att_part[row * 4 + (w & 3)] = s;
    }
  }
}

// ---------------------------------------------------------------------------
// Kernel C: per (b, e-chunk): sum 4 partials -> softmax over P -> alpha,
// awe[b][e] = sum_p alpha[p] * enc[b][p][e].  grid = B*2, block 256.
// ---------------------------------------------------------------------------
__global__ void softmax_awe_kernel(const float* __restrict__ enc,
                                   const float* __restrict__ att_part,
                                   float* __restrict__ out) {
  const int bid = blockIdx.x;
  const int b = bid >> 1, ch = bid & 1;
  const int t = threadIdx.x;
  __shared__ float sm[256];
  __shared__ float alpha_s[P_];

  float av = -1e30f;
  if (t < P_) {
    const float* apt = att_part + (b * P_ + t) * 4;
    av = (apt[0] + apt[1]) + (apt[2] + apt[3]);
  }
  sm[t] = av;
  __syncthreads();
  for (int st = 128; st > 0; st >>= 1) {
    if (t < st) sm[t] = fmaxf(sm[t], sm[t + st]);
    __syncthreads();
  }
  const float mx = sm[0];
  __syncthreads();
  float ev = 0.f;
  if (t < P_) ev = __expf(av - mx);
  sm[t] = ev;
  __syncthreads();
  for (int st = 128; st > 0; st >>= 1) {
    if (t < st) sm[t] += sm[t + st];
    __syncthreads();
  }
  const float denom = sm[0];
  const float al = ev / denom;
  if (t < P_) {
    alpha_s[t] = al;
    if (ch == 0) out[B_ * E_ + b * P_ + t] = al;   // alpha output
  }
  __syncthreads();

  const int e0 = ch * 1024 + t * 4;
  const float* ebase = enc + (size_t)b * P_ * E_ + e0;
  f32x4 acc = {0.f, 0.f, 0.f, 0.f};
  for (int p = 0; p < P_; ++p) {
    const f32x4 v = *(const f32x4*)(ebase + (size_t)p * E_);
    const float a = alpha_s[p];
    acc.x += a * v.x; acc.y += a * v.y; acc.z += a * v.z; acc.w += a * v.w;
  }
  *(f32x4*)(out + b * E_ + e0) = acc;
}

// ---------------------------------------------------------------------------
extern "C" void kernel_launch(void* const* d_in, const int* in_sizes, int n_in,
                              void* d_out, int out_size, void* d_ws, size_t ws_size,
                              hipStream_t stream) {
  const float* enc = (const float*)d_in[0];
  const float* h   = (const float*)d_in[1];
  const float* We  = (const float*)d_in[2];
  const float* be  = (const float*)d_in[3];
  const float* Wd  = (const float*)d_in[4];
  const float* bd  = (const float*)d_in[5];
  const float* Wf  = (const float*)d_in[6];
  // d_in[7] = bf: constant shift before softmax -> cancels; unused.
  float* out = (float*)d_out;

  // workspace layout (~2.7 MB)
  float* att2pb = (float*)d_ws;                       // 128*512 f32
  float* att_part = att2pb + B_ * A_;                 // 25088*4 f32
  unsigned short* WeT = (unsigned short*)(att_part + M_ * 4);  // 512*2048 u16

  we_conv_kernel<<<dim3(A_ / 32, E_ / 32), dim3(32, 32), 0, stream>>>(We, WeT);
  att2_kernel<<<B_, 256, 0, stream>>>(h, Wd, bd, be, att2pb);
  score_kernel<<<M_ / 128, 512, 0, stream>>>(enc, WeT, att2pb, Wf, att_part);
  softmax_awe_kernel<<<B_ * 2, 256, 0, stream>>>(enc, att_part, out);
}